// Round 2
// baseline (603.601 us; speedup 1.0000x reference)
//
#include <hip/hip_runtime.h>
#include <hip/hip_bf16.h>

typedef __attribute__((ext_vector_type(4))) float f32x4;
typedef __attribute__((ext_vector_type(8))) short short8;
typedef __attribute__((ext_vector_type(4))) unsigned short us4;

#define BH_ 128
#define N_ 4096
#define LOG2E 1.4426950408889634f
#define NORML (0.35355339059327373f * LOG2E)  // d^-0.25 * log2(e) folded into P
#define DIAGL (0.0625f * LOG2E)               // 0.5*d^-0.5 * log2(e)
#define EPSF 1e-4f

#if __has_builtin(__builtin_amdgcn_exp2f)
#define EXP2F(x) __builtin_amdgcn_exp2f(x)
#else
#define EXP2F(x) exp2f(x)
#endif

static __device__ __forceinline__ unsigned short f2bf(float f) {
  return __bfloat16_as_ushort(__float2bfloat16(f));  // RNE, HW cvt
}
static __device__ __forceinline__ float bf2f(unsigned short s) {
  return __uint_as_float(((unsigned int)s) << 16);
}
static __device__ __forceinline__ us4 cvt4(f32x4 x) {
  us4 r;
  r[0] = f2bf(x[0]); r[1] = f2bf(x[1]); r[2] = f2bf(x[2]); r[3] = f2bf(x[3]);
  return r;
}

// ---------------------------------------------------------------------------
// K pass (log2 domain): dd2 = K*P^T (P scaled by log2e), w = exp2(dd2-diag2)
// unshifted; ctx_partial += w^T*V; kexp/vsum partials; gmax via atomicMax.
// 2 barriers/tile: S (protect sX/sVt overwrite), A (stage visible).
// GEMM2 needs no barrier: sW region is wave-private (same-wave DS ordering).
// ---------------------------------------------------------------------------
__global__ __launch_bounds__(256, 3)
void perf_kpass(const float* __restrict__ kp, const float* __restrict__ vp,
                const float* __restrict__ proj, float* __restrict__ ctxp,
                float* __restrict__ kexpp, float* __restrict__ vsump,
                unsigned int* __restrict__ gmaxb, int nchunk) {
  const int bh = blockIdx.x & (BH_ - 1);
  const int chunk = blockIdx.x >> 7;
  const int chunkrows = N_ / nchunk;
  const int tiles = chunkrows >> 5;
  const int t = threadIdx.x;
  const int wid = t >> 6;
  const int lane = t & 63;
  const int g = lane >> 4;
  const int c = lane & 15;

  __shared__ __align__(16) unsigned short sX[32][72];
  __shared__ __align__(16) unsigned short sVt[64][40];
  __shared__ __align__(16) unsigned short sW[256][40];
  __shared__ float sDiag[32];
  __shared__ float sVsum[64];
  __shared__ float sGm[4];

  short8 pfrag[4][2];
#pragma unroll
  for (int mt = 0; mt < 4; ++mt)
#pragma unroll
    for (int kk = 0; kk < 2; ++kk) {
      const float* src = proj + (wid * 64 + mt * 16 + c) * 64 + kk * 32 + g * 8;
      short8 v;
#pragma unroll
      for (int j = 0; j < 8; ++j) v[j] = (short)f2bf(src[j] * NORML);
      pfrag[mt][kk] = v;
    }

  f32x4 ctx[4][4];
#pragma unroll
  for (int i = 0; i < 4; ++i)
#pragma unroll
    for (int j = 0; j < 4; ++j) ctx[i][j] = (f32x4){0.f, 0.f, 0.f, 0.f};

  float kexpreg[4] = {0.f, 0.f, 0.f, 0.f};
  float vsum0 = 0.f, vsum1 = 0.f, vsum2 = 0.f, vsum3 = 0.f;
  float gm = -1e30f;

  const float* kb0 = kp + ((size_t)bh * N_ + (size_t)chunk * chunkrows) * 64;
  const float* vb0 = vp + ((size_t)bh * N_ + (size_t)chunk * chunkrows) * 64;

  // prefetch tile 0
  f32x4 kx[2], vx[2];
#pragma unroll
  for (int hh = 0; hh < 2; ++hh) {
    int f = t + hh * 256;
    kx[hh] = *(const f32x4*)(kb0 + (f >> 4) * 64 + (f & 15) * 4);
    vx[hh] = *(const f32x4*)(vb0 + (f >> 4) * 64 + (f & 15) * 4);
  }

  for (int nt = 0; nt < tiles; ++nt) {
    __syncthreads();  // S: prev tile's reads of sX/sVt are complete
#pragma unroll
    for (int hh = 0; hh < 2; ++hh) {
      int f = t + hh * 256;
      int row = f >> 4;
      int c4 = f & 15;
      f32x4 x = kx[hh];
      float ss = x[0] * x[0] + x[1] * x[1] + x[2] * x[2] + x[3] * x[3];
      ss += __shfl_xor(ss, 1);
      ss += __shfl_xor(ss, 2);
      ss += __shfl_xor(ss, 4);
      ss += __shfl_xor(ss, 8);
      if (c4 == 0) sDiag[row] = DIAGL * ss;
      *(us4*)&sX[row][c4 * 4] = cvt4(x);
      f32x4 vv = vx[hh];
      vsum0 += vv[0]; vsum1 += vv[1]; vsum2 += vv[2]; vsum3 += vv[3];
#pragma unroll
      for (int jj = 0; jj < 4; ++jj) {
        int j = (jj + t) & 3;  // rotate to spread banks
        float val = (j == 0) ? vv[0] : (j == 1) ? vv[1] : (j == 2) ? vv[2] : vv[3];
        sVt[c4 * 4 + j][row] = f2bf(val);
      }
    }
    // prefetch next tile (hides under GEMM1+exp+GEMM2)
    if (nt + 1 < tiles) {
      const float* kb = kb0 + (nt + 1) * 2048;
      const float* vb = vb0 + (nt + 1) * 2048;
#pragma unroll
      for (int hh = 0; hh < 2; ++hh) {
        int f = t + hh * 256;
        kx[hh] = *(const f32x4*)(kb + (f >> 4) * 64 + (f & 15) * 4);
        vx[hh] = *(const f32x4*)(vb + (f >> 4) * 64 + (f & 15) * 4);
      }
    }
    __syncthreads();  // A: staged tile visible

    // ---- GEMM1: dd2[32n x 256m] ----
    short8 afr[2][2];
#pragma unroll
    for (int nh1 = 0; nh1 < 2; ++nh1)
#pragma unroll
      for (int kk = 0; kk < 2; ++kk)
        afr[nh1][kk] = *(const short8*)&sX[nh1 * 16 + c][kk * 32 + g * 8];

    f32x4 acc1[2][4];
#pragma unroll
    for (int i = 0; i < 2; ++i)
#pragma unroll
      for (int j = 0; j < 4; ++j) acc1[i][j] = (f32x4){0.f, 0.f, 0.f, 0.f};
#pragma unroll
    for (int kk = 0; kk < 2; ++kk)
#pragma unroll
      for (int nh1 = 0; nh1 < 2; ++nh1)
#pragma unroll
        for (int mt = 0; mt < 4; ++mt)
          acc1[nh1][mt] = __builtin_amdgcn_mfma_f32_16x16x32_bf16(
              afr[nh1][kk], pfrag[mt][kk], acc1[nh1][mt], 0, 0, 0);

    // ---- w = exp2(dd2 - diag2), write w^T (wave-private region) ----
#pragma unroll
    for (int nh1 = 0; nh1 < 2; ++nh1)
#pragma unroll
      for (int mt = 0; mt < 4; ++mt) {
        int m = wid * 64 + mt * 16 + c;
        unsigned short wp[4];
#pragma unroll
        for (int r = 0; r < 4; ++r) {
          float dd = acc1[nh1][mt][r];
          gm = fmaxf(gm, dd);
          int n = nh1 * 16 + g * 4 + r;
          float w = EXP2F(dd - sDiag[n]);
          unsigned short wb = f2bf(w);
          kexpreg[mt] += bf2f(wb);
          wp[r] = wb;
        }
        us4 w4 = {wp[0], wp[1], wp[2], wp[3]};
        *(us4*)&sW[m][nh1 * 16 + g * 4] = w4;
      }

    // ---- GEMM2: ctx[256m x 64e] += w^T * V (no barrier: own sW, sVt post-A)
    short8 awt[4], bvv[4];
#pragma unroll
    for (int mt2 = 0; mt2 < 4; ++mt2)
      awt[mt2] = *(const short8*)&sW[wid * 64 + mt2 * 16 + c][g * 8];
#pragma unroll
    for (int et = 0; et < 4; ++et)
      bvv[et] = *(const short8*)&sVt[et * 16 + c][g * 8];
#pragma unroll
    for (int mt2 = 0; mt2 < 4; ++mt2)
#pragma unroll
      for (int et = 0; et < 4; ++et)
        ctx[mt2][et] = __builtin_amdgcn_mfma_f32_16x16x32_bf16(
            awt[mt2], bvv[et], ctx[mt2][et], 0, 0, 0);
  }

  // ---- epilogue: partials ----
#pragma unroll
  for (int mt2 = 0; mt2 < 4; ++mt2)
#pragma unroll
    for (int et = 0; et < 4; ++et) {
      int m0 = wid * 64 + mt2 * 16 + g * 4;
      int e = et * 16 + c;
      size_t base = (((size_t)chunk * BH_ + bh) * 64 + e) * 256 + m0;
      *(f32x4*)(ctxp + base) = ctx[mt2][et];
    }
#pragma unroll
  for (int mt = 0; mt < 4; ++mt) {
    float s = kexpreg[mt];
    s += __shfl_xor(s, 16);
    s += __shfl_xor(s, 32);
    if (lane < 16)
      kexpp[((size_t)chunk * BH_ + bh) * 256 + wid * 64 + mt * 16 + lane] = s;
  }
  if (t < 64) sVsum[t] = 0.f;
  __syncthreads();
  atomicAdd(&sVsum[(t & 15) * 4 + 0], vsum0);
  atomicAdd(&sVsum[(t & 15) * 4 + 1], vsum1);
  atomicAdd(&sVsum[(t & 15) * 4 + 2], vsum2);
  atomicAdd(&sVsum[(t & 15) * 4 + 3], vsum3);
  __syncthreads();
  if (t < 64) vsump[((size_t)chunk * BH_ + bh) * 64 + t] = sVsum[t];

  gm = fmaxf(gm, __shfl_xor(gm, 1));
  gm = fmaxf(gm, __shfl_xor(gm, 2));
  gm = fmaxf(gm, __shfl_xor(gm, 4));
  gm = fmaxf(gm, __shfl_xor(gm, 8));
  gm = fmaxf(gm, __shfl_xor(gm, 16));
  gm = fmaxf(gm, __shfl_xor(gm, 32));
  if (lane == 0) sGm[wid] = gm;
  __syncthreads();
  if (t == 0) {
    float mm = fmaxf(fmaxf(sGm[0], sGm[1]), fmaxf(sGm[2], sGm[3]));
    atomicMax((int*)gmaxb, __float_as_int(mm));  // gmax2 > 0 in practice
  }
}

// ---------------------------------------------------------------------------
// Rescale (parallel over bh x e-slice): CTX = 2^-g * sum(ctx) + eps*vsum,
// KC = 2^-g * sum(kexp) + eps*N.
// ---------------------------------------------------------------------------
__global__ void perf_rescale(const float* __restrict__ ctxp,
                             const float* __restrict__ kexpp,
                             const float* __restrict__ vsump,
                             float* __restrict__ kcw,
                             unsigned short* __restrict__ ctxt,
                             const unsigned int* __restrict__ gmaxb, int nchunk) {
  const int bh = blockIdx.x >> 3;
  const int es = blockIdx.x & 7;
  const int t = threadIdx.x;  // m
  const float gmax = __uint_as_float(*gmaxb);
  const float s = EXP2F(-gmax);
  if (es == 0) {
    float acc = 0.f;
    for (int cc = 0; cc < nchunk; ++cc)
      acc += kexpp[((size_t)cc * BH_ + bh) * 256 + t];
    kcw[bh * 256 + t] = s * acc + EPSF * (float)N_;
  }
  for (int e = es * 8; e < es * 8 + 8; ++e) {
    float vs = 0.f;
    for (int cc = 0; cc < nchunk; ++cc)
      vs += vsump[((size_t)cc * BH_ + bh) * 64 + e];
    float a2 = 0.f;
    for (int cc = 0; cc < nchunk; ++cc)
      a2 += ctxp[(((size_t)cc * BH_ + bh) * 64 + e) * 256 + t];
    ctxt[((size_t)bh * 64 + e) * 256 + t] = f2bf(s * a2 + EPSF * vs);
  }
}

// ---------------------------------------------------------------------------
// Q pass: dd2 = Q*P^T, rowmax (log2 domain), qt = exp2(dd2-diag2-rmax)+eps,
// den = qt.KC, out = (qt*CTX)/den. 3 barriers/tile, prefetched staging.
// ---------------------------------------------------------------------------
__global__ __launch_bounds__(256, 4)
void perf_qpass(const float* __restrict__ qp, const float* __restrict__ proj,
                const unsigned short* __restrict__ ctxt,
                const float* __restrict__ kc, float* __restrict__ outp) {
  const int bh = blockIdx.x & (BH_ - 1);
  const int chunk = blockIdx.x >> 7;  // 0..15, 256 rows each
  const int t = threadIdx.x;
  const int wid = t >> 6;
  const int lane = t & 63;
  const int g = lane >> 4;
  const int c = lane & 15;
  const int nh = wid >> 1;
  const int ep = wid & 1;

  __shared__ __align__(16) unsigned short sX[32][72];
  __shared__ __align__(16) unsigned short sQt[32][264];
  __shared__ float sDiag[32];
  __shared__ float sRowPart[4][33];
  __shared__ float sDenPart[4][33];

  short8 pfrag[4][2];
#pragma unroll
  for (int mt = 0; mt < 4; ++mt)
#pragma unroll
    for (int kk = 0; kk < 2; ++kk) {
      const float* src = proj + (wid * 64 + mt * 16 + c) * 64 + kk * 32 + g * 8;
      short8 v;
#pragma unroll
      for (int j = 0; j < 8; ++j) v[j] = (short)f2bf(src[j] * NORML);
      pfrag[mt][kk] = v;
    }

  short8 cfrag[2][8];
#pragma unroll
  for (int fi = 0; fi < 2; ++fi)
#pragma unroll
    for (int kk2 = 0; kk2 < 8; ++kk2)
      cfrag[fi][kk2] = *(const short8*)&ctxt[(((size_t)bh * 64) +
                                             (ep * 2 + fi) * 16 + c) * 256 +
                                            kk2 * 32 + g * 8];
  float kcreg[4];
#pragma unroll
  for (int mt = 0; mt < 4; ++mt)
    kcreg[mt] = kc[bh * 256 + wid * 64 + mt * 16 + c];

  const float* qb0 = qp + ((size_t)bh * N_ + (size_t)chunk * 256) * 64;
  float* ob0 = outp + ((size_t)bh * N_ + (size_t)chunk * 256) * 64;

  f32x4 qx[2];
#pragma unroll
  for (int hh = 0; hh < 2; ++hh) {
    int f = t + hh * 256;
    qx[hh] = *(const f32x4*)(qb0 + (f >> 4) * 64 + (f & 15) * 4);
  }

  for (int nt = 0; nt < 8; ++nt) {
#pragma unroll
    for (int hh = 0; hh < 2; ++hh) {
      int f = t + hh * 256;
      int row = f >> 4;
      int c4 = f & 15;
      f32x4 x = qx[hh];
      float ss = x[0] * x[0] + x[1] * x[1] + x[2] * x[2] + x[3] * x[3];
      ss += __shfl_xor(ss, 1);
      ss += __shfl_xor(ss, 2);
      ss += __shfl_xor(ss, 4);
      ss += __shfl_xor(ss, 8);
      if (c4 == 0) sDiag[row] = DIAGL * ss;
      *(us4*)&sX[row][c4 * 4] = cvt4(x);
    }
    if (nt + 1 < 8) {
      const float* qb = qb0 + (nt + 1) * 2048;
#pragma unroll
      for (int hh = 0; hh < 2; ++hh) {
        int f = t + hh * 256;
        qx[hh] = *(const f32x4*)(qb + (f >> 4) * 64 + (f & 15) * 4);
      }
    }
    __syncthreads();  // b1: sX/sDiag staged

    short8 afr[2][2];
#pragma unroll
    for (int nh1 = 0; nh1 < 2; ++nh1)
#pragma unroll
      for (int kk = 0; kk < 2; ++kk)
        afr[nh1][kk] = *(const short8*)&sX[nh1 * 16 + c][kk * 32 + g * 8];
    f32x4 acc1[2][4];
#pragma unroll
    for (int i = 0; i < 2; ++i)
#pragma unroll
      for (int j = 0; j < 4; ++j) acc1[i][j] = (f32x4){0.f, 0.f, 0.f, 0.f};
#pragma unroll
    for (int kk = 0; kk < 2; ++kk)
#pragma unroll
      for (int nh1 = 0; nh1 < 2; ++nh1)
#pragma unroll
        for (int mt = 0; mt < 4; ++mt)
          acc1[nh1][mt] = __builtin_amdgcn_mfma_f32_16x16x32_bf16(
              afr[nh1][kk], pfrag[mt][kk], acc1[nh1][mt], 0, 0, 0);

    // rowmax partials (wave-local over 64 m)
#pragma unroll
    for (int nh1 = 0; nh1 < 2; ++nh1)
#pragma unroll
      for (int r = 0; r < 4; ++r) {
        float mx = fmaxf(fmaxf(acc1[nh1][0][r], acc1[nh1][1][r]),
                         fmaxf(acc1[nh1][2][r], acc1[nh1][3][r]));
        mx = fmaxf(mx, __shfl_xor(mx, 1));
        mx = fmaxf(mx, __shfl_xor(mx, 2));
        mx = fmaxf(mx, __shfl_xor(mx, 4));
        mx = fmaxf(mx, __shfl_xor(mx, 8));
        if (c == 0) sRowPart[wid][nh1 * 16 + g * 4 + r] = mx;
      }
    __syncthreads();  // b2: rowmax partials visible

    // qt = exp2(dd2 - diag2 - rmax2) + eps ; den partials
    float base[2][4];
#pragma unroll
    for (int nh1 = 0; nh1 < 2; ++nh1)
#pragma unroll
      for (int r = 0; r < 4; ++r) {
        int n = nh1 * 16 + g * 4 + r;
        float rm = fmaxf(fmaxf(sRowPart[0][n], sRowPart[1][n]),
                         fmaxf(sRowPart[2][n], sRowPart[3][n]));
        base[nh1][r] = sDiag[n] + rm;
      }
    unsigned short qtv[2][4][4];
    float denp[2][4];
#pragma unroll
    for (int nh1 = 0; nh1 < 2; ++nh1)
#pragma unroll
      for (int r = 0; r < 4; ++r) denp[nh1][r] = 0.f;
#pragma unroll
    for (int nh1 = 0; nh1 < 2; ++nh1)
#pragma unroll
      for (int mt = 0; mt < 4; ++mt)
#pragma unroll
        for (int r = 0; r < 4; ++r) {
          float qt = EXP2F(acc1[nh1][mt][r] - base[nh1][r]) + EPSF;
          unsigned short qb16 = f2bf(qt);
          denp[nh1][r] += bf2f(qb16) * kcreg[mt];
          qtv[nh1][mt][r] = qb16;
        }
#pragma unroll
    for (int nh1 = 0; nh1 < 2; ++nh1)
#pragma unroll
      for (int mt = 0; mt < 4; ++mt)
#pragma unroll
        for (int r = 0; r < 4; ++r)
          sQt[nh1 * 16 + g * 4 + r][wid * 64 + mt * 16 + c] = qtv[nh1][mt][r];
#pragma unroll
    for (int nh1 = 0; nh1 < 2; ++nh1)
#pragma unroll
      for (int r = 0; r < 4; ++r) {
        float s = denp[nh1][r];
        s += __shfl_xor(s, 1);
        s += __shfl_xor(s, 2);
        s += __shfl_xor(s, 4);
        s += __shfl_xor(s, 8);
        if (c == 0) sDenPart[wid][nh1 * 16 + g * 4 + r] = s;
      }
    __syncthreads();  // b3: sQt/sDenPart visible

    // GEMM2: out[32n x 64e]; wave owns (n-half, e-pair)
    f32x4 acc2[2];
    acc2[0] = (f32x4){0.f, 0.f, 0.f, 0.f};
    acc2[1] = (f32x4){0.f, 0.f, 0.f, 0.f};
#pragma unroll
    for (int kk2 = 0; kk2 < 8; ++kk2) {
      short8 a2 = *(const short8*)&sQt[nh * 16 + c][kk2 * 32 + g * 8];
      acc2[0] = __builtin_amdgcn_mfma_f32_16x16x32_bf16(a2, cfrag[0][kk2], acc2[0], 0, 0, 0);
      acc2[1] = __builtin_amdgcn_mfma_f32_16x16x32_bf16(a2, cfrag[1][kk2], acc2[1], 0, 0, 0);
    }
#pragma unroll
    for (int r = 0; r < 4; ++r) {
      int n = nh * 16 + g * 4 + r;
      float den = sDenPart[0][n] + sDenPart[1][n] + sDenPart[2][n] + sDenPart[3][n];
      float rinv = 1.0f / den;
#pragma unroll
      for (int fi = 0; fi < 2; ++fi) {
        int e = (ep * 2 + fi) * 16 + c;
        ob0[((size_t)(nt * 32 + n)) * 64 + e] = acc2[fi][r] * rinv;
      }
    }
    // no trailing barrier: next stage's sX writes are fenced by b1/b2/b3 chain
  }
}

extern "C" void kernel_launch(void* const* d_in, const int* in_sizes, int n_in,
                              void* d_out, int out_size, void* d_ws, size_t ws_size,
                              hipStream_t stream) {
  (void)in_sizes; (void)n_in; (void)out_size;
  const float* qp = (const float*)d_in[0];
  const float* kp = (const float*)d_in[1];
  const float* vp = (const float*)d_in[2];
  const float* proj = (const float*)d_in[3];
  float* outp = (float*)d_out;

  int nchunk = 8;
  while (nchunk > 1) {
    size_t fl = 64 + (size_t)nchunk * (2097152 + 32768 + 8192) + 32768;
    size_t needed = fl * 4 + (size_t)128 * 64 * 256 * 2;
    if (needed <= ws_size) break;
    nchunk >>= 1;
  }

  float* wsf = (float*)d_ws;
  unsigned int* gmaxb = (unsigned int*)d_ws;
  float* ctxp = wsf + 64;
  float* kexpp = ctxp + (size_t)nchunk * 128 * 64 * 256;
  float* vsump = kexpp + (size_t)nchunk * 128 * 256;
  float* kcw = vsump + (size_t)nchunk * 128 * 64;
  unsigned short* ctxt = (unsigned short*)(kcw + 128 * 256);

  hipMemsetAsync(d_ws, 0, 16, stream);
  hipLaunchKernelGGL(perf_kpass, dim3(128 * nchunk), dim3(256), 0, stream,
                     kp, vp, proj, ctxp, kexpp, vsump, gmaxb, nchunk);
  hipLaunchKernelGGL(perf_rescale, dim3(128 * 8), dim3(256), 0, stream,
                     ctxp, kexpp, vsump, kcw, ctxt, gmaxb, nchunk);
  hipLaunchKernelGGL(perf_qpass, dim3(128 * 16), dim3(256), 0, stream,
                     qp, proj, ctxt, kcw, outp);
}

// Round 3
// 308.988 us; speedup vs baseline: 1.9535x; 1.9535x over previous
//
#include <hip/hip_runtime.h>
#include <hip/hip_bf16.h>

typedef __attribute__((ext_vector_type(4))) float f32x4;
typedef __attribute__((ext_vector_type(8))) short short8;
typedef __attribute__((ext_vector_type(4))) unsigned short us4;

#define BH_ 128
#define N_ 4096
#define LOG2E 1.4426950408889634f
#define NORML (0.35355339059327373f * LOG2E)  // d^-0.25 * log2(e) folded into P
#define DIAGL (0.0625f * LOG2E)               // 0.5*d^-0.5 * log2(e)
#define EPSF 1e-4f

#if __has_builtin(__builtin_amdgcn_exp2f)
#define EXP2F(x) __builtin_amdgcn_exp2f(x)
#else
#define EXP2F(x) exp2f(x)
#endif

static __device__ __forceinline__ unsigned short f2bf(float f) {
  return __bfloat16_as_ushort(__float2bfloat16(f));  // RNE, HW cvt
}
static __device__ __forceinline__ float bf2f(unsigned short s) {
  return __uint_as_float(((unsigned int)s) << 16);
}
static __device__ __forceinline__ us4 cvt4(f32x4 x) {
  us4 r;
  r[0] = f2bf(x[0]); r[1] = f2bf(x[1]); r[2] = f2bf(x[2]); r[3] = f2bf(x[3]);
  return r;
}

// ---------------------------------------------------------------------------
// K pass (log2 domain): dd2 = K*P^T (P scaled by log2e), w = exp2(dd2-diag2)
// unshifted; ctx_partial += w^T*V; kexp/vsum partials; gmax via atomicMax.
// 2 barriers/tile. GEMM2 reads wave-private sW region (same-wave DS order).
// __launch_bounds__(256,2): min-waves 2/EU only — higher caps cause VGPR
// spills (round-2 post-mortem: FETCH 454MB vs 280MB ideal, scratch-bound).
// ---------------------------------------------------------------------------
__global__ __launch_bounds__(256, 2)
void perf_kpass(const float* __restrict__ kp, const float* __restrict__ vp,
                const float* __restrict__ proj, float* __restrict__ ctxp,
                float* __restrict__ kexpp, float* __restrict__ vsump,
                unsigned int* __restrict__ gmaxb, int nchunk) {
  const int bh = blockIdx.x & (BH_ - 1);
  const int chunk = blockIdx.x >> 7;
  const int chunkrows = N_ / nchunk;
  const int tiles = chunkrows >> 5;
  const int t = threadIdx.x;
  const int wid = t >> 6;
  const int lane = t & 63;
  const int g = lane >> 4;
  const int c = lane & 15;

  __shared__ __align__(16) unsigned short sX[32][72];
  __shared__ __align__(16) unsigned short sVt[64][40];
  __shared__ __align__(16) unsigned short sW[256][40];
  __shared__ float sDiag[32];
  __shared__ float sVsum[64];
  __shared__ float sGm[4];

  short8 pfrag[4][2];
#pragma unroll
  for (int mt = 0; mt < 4; ++mt)
#pragma unroll
    for (int kk = 0; kk < 2; ++kk) {
      const float* src = proj + (wid * 64 + mt * 16 + c) * 64 + kk * 32 + g * 8;
      short8 v;
#pragma unroll
      for (int j = 0; j < 8; ++j) v[j] = (short)f2bf(src[j] * NORML);
      pfrag[mt][kk] = v;
    }

  f32x4 ctx[4][4];
#pragma unroll
  for (int i = 0; i < 4; ++i)
#pragma unroll
    for (int j = 0; j < 4; ++j) ctx[i][j] = (f32x4){0.f, 0.f, 0.f, 0.f};

  float kexpreg[4] = {0.f, 0.f, 0.f, 0.f};
  float vsum0 = 0.f, vsum1 = 0.f, vsum2 = 0.f, vsum3 = 0.f;
  float gm = -1e30f;

  const float* kb0 = kp + ((size_t)bh * N_ + (size_t)chunk * chunkrows) * 64;
  const float* vb0 = vp + ((size_t)bh * N_ + (size_t)chunk * chunkrows) * 64;

  // prefetch tile 0
  f32x4 kx[2], vx[2];
#pragma unroll
  for (int hh = 0; hh < 2; ++hh) {
    int f = t + hh * 256;
    kx[hh] = *(const f32x4*)(kb0 + (f >> 4) * 64 + (f & 15) * 4);
    vx[hh] = *(const f32x4*)(vb0 + (f >> 4) * 64 + (f & 15) * 4);
  }

  for (int nt = 0; nt < tiles; ++nt) {
    __syncthreads();  // S: prev tile's reads of sX/sVt complete
#pragma unroll
    for (int hh = 0; hh < 2; ++hh) {
      int f = t + hh * 256;
      int row = f >> 4;
      int c4 = f & 15;
      f32x4 x = kx[hh];
      float ss = x[0] * x[0] + x[1] * x[1] + x[2] * x[2] + x[3] * x[3];
      ss += __shfl_xor(ss, 1);
      ss += __shfl_xor(ss, 2);
      ss += __shfl_xor(ss, 4);
      ss += __shfl_xor(ss, 8);
      if (c4 == 0) sDiag[row] = DIAGL * ss;
      *(us4*)&sX[row][c4 * 4] = cvt4(x);
      f32x4 vv = vx[hh];
      vsum0 += vv[0]; vsum1 += vv[1]; vsum2 += vv[2]; vsum3 += vv[3];
#pragma unroll
      for (int jj = 0; jj < 4; ++jj) {
        int j = (jj + t) & 3;  // rotate to spread banks
        float val = (j == 0) ? vv[0] : (j == 1) ? vv[1] : (j == 2) ? vv[2] : vv[3];
        sVt[c4 * 4 + j][row] = f2bf(val);
      }
    }
    // prefetch next tile (hides under GEMM1+exp+GEMM2)
    if (nt + 1 < tiles) {
      const float* kb = kb0 + (nt + 1) * 2048;
      const float* vb = vb0 + (nt + 1) * 2048;
#pragma unroll
      for (int hh = 0; hh < 2; ++hh) {
        int f = t + hh * 256;
        kx[hh] = *(const f32x4*)(kb + (f >> 4) * 64 + (f & 15) * 4);
        vx[hh] = *(const f32x4*)(vb + (f >> 4) * 64 + (f & 15) * 4);
      }
    }
    __syncthreads();  // A: staged tile visible

    // ---- GEMM1: dd2[32n x 256m] ----
    short8 afr[2][2];
#pragma unroll
    for (int nh1 = 0; nh1 < 2; ++nh1)
#pragma unroll
      for (int kk = 0; kk < 2; ++kk)
        afr[nh1][kk] = *(const short8*)&sX[nh1 * 16 + c][kk * 32 + g * 8];

    f32x4 acc1[2][4];
#pragma unroll
    for (int i = 0; i < 2; ++i)
#pragma unroll
      for (int j = 0; j < 4; ++j) acc1[i][j] = (f32x4){0.f, 0.f, 0.f, 0.f};
#pragma unroll
    for (int kk = 0; kk < 2; ++kk)
#pragma unroll
      for (int nh1 = 0; nh1 < 2; ++nh1)
#pragma unroll
        for (int mt = 0; mt < 4; ++mt)
          acc1[nh1][mt] = __builtin_amdgcn_mfma_f32_16x16x32_bf16(
              afr[nh1][kk], pfrag[mt][kk], acc1[nh1][mt], 0, 0, 0);

    // ---- w = exp2(dd2 - diag2), write w^T (wave-private region) ----
#pragma unroll
    for (int nh1 = 0; nh1 < 2; ++nh1)
#pragma unroll
      for (int mt = 0; mt < 4; ++mt) {
        int m = wid * 64 + mt * 16 + c;
        unsigned short wp[4];
#pragma unroll
        for (int r = 0; r < 4; ++r) {
          float dd = acc1[nh1][mt][r];
          gm = fmaxf(gm, dd);
          int n = nh1 * 16 + g * 4 + r;
          float w = EXP2F(dd - sDiag[n]);
          unsigned short wb = f2bf(w);
          kexpreg[mt] += bf2f(wb);
          wp[r] = wb;
        }
        us4 w4 = {wp[0], wp[1], wp[2], wp[3]};
        *(us4*)&sW[m][nh1 * 16 + g * 4] = w4;
      }

    // ---- GEMM2: ctx[256m x 64e] += w^T * V (no barrier needed) ----
    short8 awt[4], bvv[4];
#pragma unroll
    for (int mt2 = 0; mt2 < 4; ++mt2)
      awt[mt2] = *(const short8*)&sW[wid * 64 + mt2 * 16 + c][g * 8];
#pragma unroll
    for (int et = 0; et < 4; ++et)
      bvv[et] = *(const short8*)&sVt[et * 16 + c][g * 8];
#pragma unroll
    for (int mt2 = 0; mt2 < 4; ++mt2)
#pragma unroll
      for (int et = 0; et < 4; ++et)
        ctx[mt2][et] = __builtin_amdgcn_mfma_f32_16x16x32_bf16(
            awt[mt2], bvv[et], ctx[mt2][et], 0, 0, 0);
  }

  // ---- epilogue: partials ----
#pragma unroll
  for (int mt2 = 0; mt2 < 4; ++mt2)
#pragma unroll
    for (int et = 0; et < 4; ++et) {
      int m0 = wid * 64 + mt2 * 16 + g * 4;
      int e = et * 16 + c;
      size_t base = (((size_t)chunk * BH_ + bh) * 64 + e) * 256 + m0;
      *(f32x4*)(ctxp + base) = ctx[mt2][et];
    }
#pragma unroll
  for (int mt = 0; mt < 4; ++mt) {
    float s = kexpreg[mt];
    s += __shfl_xor(s, 16);
    s += __shfl_xor(s, 32);
    if (lane < 16)
      kexpp[((size_t)chunk * BH_ + bh) * 256 + wid * 64 + mt * 16 + lane] = s;
  }
  if (t < 64) sVsum[t] = 0.f;
  __syncthreads();
  atomicAdd(&sVsum[(t & 15) * 4 + 0], vsum0);
  atomicAdd(&sVsum[(t & 15) * 4 + 1], vsum1);
  atomicAdd(&sVsum[(t & 15) * 4 + 2], vsum2);
  atomicAdd(&sVsum[(t & 15) * 4 + 3], vsum3);
  __syncthreads();
  if (t < 64) vsump[((size_t)chunk * BH_ + bh) * 64 + t] = sVsum[t];

  gm = fmaxf(gm, __shfl_xor(gm, 1));
  gm = fmaxf(gm, __shfl_xor(gm, 2));
  gm = fmaxf(gm, __shfl_xor(gm, 4));
  gm = fmaxf(gm, __shfl_xor(gm, 8));
  gm = fmaxf(gm, __shfl_xor(gm, 16));
  gm = fmaxf(gm, __shfl_xor(gm, 32));
  if (lane == 0) sGm[wid] = gm;
  __syncthreads();
  if (t == 0) {
    float mm = fmaxf(fmaxf(sGm[0], sGm[1]), fmaxf(sGm[2], sGm[3]));
    atomicMax((int*)gmaxb, __float_as_int(mm));  // gmax2 > 0 in practice
  }
}

// ---------------------------------------------------------------------------
// Rescale (parallel over bh x e-slice): CTX = 2^-g * sum(ctx) + eps*vsum,
// KC = 2^-g * sum(kexp) + eps*N.
// ---------------------------------------------------------------------------
__global__ void perf_rescale(const float* __restrict__ ctxp,
                             const float* __restrict__ kexpp,
                             const float* __restrict__ vsump,
                             float* __restrict__ kcw,
                             unsigned short* __restrict__ ctxt,
                             const unsigned int* __restrict__ gmaxb, int nchunk) {
  const int bh = blockIdx.x >> 3;
  const int es = blockIdx.x & 7;
  const int t = threadIdx.x;  // m
  const float gmax = __uint_as_float(*gmaxb);
  const float s = EXP2F(-gmax);
  if (es == 0) {
    float acc = 0.f;
    for (int cc = 0; cc < nchunk; ++cc)
      acc += kexpp[((size_t)cc * BH_ + bh) * 256 + t];
    kcw[bh * 256 + t] = s * acc + EPSF * (float)N_;
  }
  for (int e = es * 8; e < es * 8 + 8; ++e) {
    float vs = 0.f;
    for (int cc = 0; cc < nchunk; ++cc)
      vs += vsump[((size_t)cc * BH_ + bh) * 64 + e];
    float a2 = 0.f;
    for (int cc = 0; cc < nchunk; ++cc)
      a2 += ctxp[(((size_t)cc * BH_ + bh) * 64 + e) * 256 + t];
    ctxt[((size_t)bh * 64 + e) * 256 + t] = f2bf(s * a2 + EPSF * vs);
  }
}

// ---------------------------------------------------------------------------
// Q pass: dd2 = Q*P^T, rowmax (log2 domain), qt = exp2(dd2-diag2-rmax)+eps,
// den = qt.KC, out = (qt*CTX)/den. 3 barriers/tile, prefetched staging.
// __launch_bounds__(256,2): (256,4) spilled cfrag (64 VGPRs) -> 606MB FETCH.
// ---------------------------------------------------------------------------
__global__ __launch_bounds__(256, 2)
void perf_qpass(const float* __restrict__ qp, const float* __restrict__ proj,
                const unsigned short* __restrict__ ctxt,
                const float* __restrict__ kc, float* __restrict__ outp) {
  const int bh = blockIdx.x & (BH_ - 1);
  const int chunk = blockIdx.x >> 7;  // 0..15, 256 rows each
  const int t = threadIdx.x;
  const int wid = t >> 6;
  const int lane = t & 63;
  const int g = lane >> 4;
  const int c = lane & 15;
  const int nh = wid >> 1;
  const int ep = wid & 1;

  __shared__ __align__(16) unsigned short sX[32][72];
  __shared__ __align__(16) unsigned short sQt[32][264];
  __shared__ float sDiag[32];
  __shared__ float sRowPart[4][33];
  __shared__ float sDenPart[4][33];

  short8 pfrag[4][2];
#pragma unroll
  for (int mt = 0; mt < 4; ++mt)
#pragma unroll
    for (int kk = 0; kk < 2; ++kk) {
      const float* src = proj + (wid * 64 + mt * 16 + c) * 64 + kk * 32 + g * 8;
      short8 v;
#pragma unroll
      for (int j = 0; j < 8; ++j) v[j] = (short)f2bf(src[j] * NORML);
      pfrag[mt][kk] = v;
    }

  short8 cfrag[2][8];
#pragma unroll
  for (int fi = 0; fi < 2; ++fi)
#pragma unroll
    for (int kk2 = 0; kk2 < 8; ++kk2)
      cfrag[fi][kk2] = *(const short8*)&ctxt[(((size_t)bh * 64) +
                                             (ep * 2 + fi) * 16 + c) * 256 +
                                            kk2 * 32 + g * 8];
  float kcreg[4];
#pragma unroll
  for (int mt = 0; mt < 4; ++mt)
    kcreg[mt] = kc[bh * 256 + wid * 64 + mt * 16 + c];

  const float* qb0 = qp + ((size_t)bh * N_ + (size_t)chunk * 256) * 64;
  float* ob0 = outp + ((size_t)bh * N_ + (size_t)chunk * 256) * 64;

  f32x4 qx[2];
#pragma unroll
  for (int hh = 0; hh < 2; ++hh) {
    int f = t + hh * 256;
    qx[hh] = *(const f32x4*)(qb0 + (f >> 4) * 64 + (f & 15) * 4);
  }

  for (int nt = 0; nt < 8; ++nt) {
#pragma unroll
    for (int hh = 0; hh < 2; ++hh) {
      int f = t + hh * 256;
      int row = f >> 4;
      int c4 = f & 15;
      f32x4 x = qx[hh];
      float ss = x[0] * x[0] + x[1] * x[1] + x[2] * x[2] + x[3] * x[3];
      ss += __shfl_xor(ss, 1);
      ss += __shfl_xor(ss, 2);
      ss += __shfl_xor(ss, 4);
      ss += __shfl_xor(ss, 8);
      if (c4 == 0) sDiag[row] = DIAGL * ss;
      *(us4*)&sX[row][c4 * 4] = cvt4(x);
    }
    if (nt + 1 < 8) {
      const float* qb = qb0 + (nt + 1) * 2048;
#pragma unroll
      for (int hh = 0; hh < 2; ++hh) {
        int f = t + hh * 256;
        qx[hh] = *(const f32x4*)(qb + (f >> 4) * 64 + (f & 15) * 4);
      }
    }
    __syncthreads();  // b1: sX/sDiag staged

    short8 afr[2][2];
#pragma unroll
    for (int nh1 = 0; nh1 < 2; ++nh1)
#pragma unroll
      for (int kk = 0; kk < 2; ++kk)
        afr[nh1][kk] = *(const short8*)&sX[nh1 * 16 + c][kk * 32 + g * 8];
    f32x4 acc1[2][4];
#pragma unroll
    for (int i = 0; i < 2; ++i)
#pragma unroll
      for (int j = 0; j < 4; ++j) acc1[i][j] = (f32x4){0.f, 0.f, 0.f, 0.f};
#pragma unroll
    for (int kk = 0; kk < 2; ++kk)
#pragma unroll
      for (int nh1 = 0; nh1 < 2; ++nh1)
#pragma unroll
        for (int mt = 0; mt < 4; ++mt)
          acc1[nh1][mt] = __builtin_amdgcn_mfma_f32_16x16x32_bf16(
              afr[nh1][kk], pfrag[mt][kk], acc1[nh1][mt], 0, 0, 0);

    // rowmax partials (wave-local over 64 m)
#pragma unroll
    for (int nh1 = 0; nh1 < 2; ++nh1)
#pragma unroll
      for (int r = 0; r < 4; ++r) {
        float mx = fmaxf(fmaxf(acc1[nh1][0][r], acc1[nh1][1][r]),
                         fmaxf(acc1[nh1][2][r], acc1[nh1][3][r]));
        mx = fmaxf(mx, __shfl_xor(mx, 1));
        mx = fmaxf(mx, __shfl_xor(mx, 2));
        mx = fmaxf(mx, __shfl_xor(mx, 4));
        mx = fmaxf(mx, __shfl_xor(mx, 8));
        if (c == 0) sRowPart[wid][nh1 * 16 + g * 4 + r] = mx;
      }
    __syncthreads();  // b2: rowmax partials visible

    float base[2][4];
#pragma unroll
    for (int nh1 = 0; nh1 < 2; ++nh1)
#pragma unroll
      for (int r = 0; r < 4; ++r) {
        int n = nh1 * 16 + g * 4 + r;
        float rm = fmaxf(fmaxf(sRowPart[0][n], sRowPart[1][n]),
                         fmaxf(sRowPart[2][n], sRowPart[3][n]));
        base[nh1][r] = sDiag[n] + rm;
      }
    unsigned short qtv[2][4][4];
    float denp[2][4];
#pragma unroll
    for (int nh1 = 0; nh1 < 2; ++nh1)
#pragma unroll
      for (int r = 0; r < 4; ++r) denp[nh1][r] = 0.f;
#pragma unroll
    for (int nh1 = 0; nh1 < 2; ++nh1)
#pragma unroll
      for (int mt = 0; mt < 4; ++mt)
#pragma unroll
        for (int r = 0; r < 4; ++r) {
          float qt = EXP2F(acc1[nh1][mt][r] - base[nh1][r]) + EPSF;
          unsigned short qb16 = f2bf(qt);
          denp[nh1][r] += bf2f(qb16) * kcreg[mt];
          qtv[nh1][mt][r] = qb16;
        }
#pragma unroll
    for (int nh1 = 0; nh1 < 2; ++nh1)
#pragma unroll
      for (int mt = 0; mt < 4; ++mt)
#pragma unroll
        for (int r = 0; r < 4; ++r)
          sQt[nh1 * 16 + g * 4 + r][wid * 64 + mt * 16 + c] = qtv[nh1][mt][r];
#pragma unroll
    for (int nh1 = 0; nh1 < 2; ++nh1)
#pragma unroll
      for (int r = 0; r < 4; ++r) {
        float s = denp[nh1][r];
        s += __shfl_xor(s, 1);
        s += __shfl_xor(s, 2);
        s += __shfl_xor(s, 4);
        s += __shfl_xor(s, 8);
        if (c == 0) sDenPart[wid][nh1 * 16 + g * 4 + r] = s;
      }
    __syncthreads();  // b3: sQt/sDenPart visible

    // GEMM2: out[32n x 64e]; wave owns (n-half, e-pair)
    f32x4 acc2[2];
    acc2[0] = (f32x4){0.f, 0.f, 0.f, 0.f};
    acc2[1] = (f32x4){0.f, 0.f, 0.f, 0.f};
#pragma unroll
    for (int kk2 = 0; kk2 < 8; ++kk2) {
      short8 a2 = *(const short8*)&sQt[nh * 16 + c][kk2 * 32 + g * 8];
      acc2[0] = __builtin_amdgcn_mfma_f32_16x16x32_bf16(a2, cfrag[0][kk2], acc2[0], 0, 0, 0);
      acc2[1] = __builtin_amdgcn_mfma_f32_16x16x32_bf16(a2, cfrag[1][kk2], acc2[1], 0, 0, 0);
    }
#pragma unroll
    for (int r = 0; r < 4; ++r) {
      int n = nh * 16 + g * 4 + r;
      float den = sDenPart[0][n] + sDenPart[1][n] + sDenPart[2][n] + sDenPart[3][n];
      float rinv = 1.0f / den;
#pragma unroll
      for (int fi = 0; fi < 2; ++fi) {
        int e = (ep * 2 + fi) * 16 + c;
        ob0[((size_t)(nt * 32 + n)) * 64 + e] = acc2[fi][r] * rinv;
      }
    }
    // no trailing barrier: iteration nt+1's sX/sDiag writes only occur after
    // b3(nt); all reads of sX/sDiag in iteration nt precede b3(nt).
  }
}

extern "C" void kernel_launch(void* const* d_in, const int* in_sizes, int n_in,
                              void* d_out, int out_size, void* d_ws, size_t ws_size,
                              hipStream_t stream) {
  (void)in_sizes; (void)n_in; (void)out_size;
  const float* qp = (const float*)d_in[0];
  const float* kp = (const float*)d_in[1];
  const float* vp = (const float*)d_in[2];
  const float* proj = (const float*)d_in[3];
  float* outp = (float*)d_out;

  int nchunk = 8;
  while (nchunk > 1) {
    size_t fl = 64 + (size_t)nchunk * (2097152 + 32768 + 8192) + 32768;
    size_t needed = fl * 4 + (size_t)128 * 64 * 256 * 2;
    if (needed <= ws_size) break;
    nchunk >>= 1;
  }

  float* wsf = (float*)d_ws;
  unsigned int* gmaxb = (unsigned int*)d_ws;
  float* ctxp = wsf + 64;
  float* kexpp = ctxp + (size_t)nchunk * 128 * 64 * 256;
  float* vsump = kexpp + (size_t)nchunk * 128 * 256;
  float* kcw = vsump + (size_t)nchunk * 128 * 64;
  unsigned short* ctxt = (unsigned short*)(kcw + 128 * 256);

  hipMemsetAsync(d_ws, 0, 16, stream);
  hipLaunchKernelGGL(perf_kpass, dim3(128 * nchunk), dim3(256), 0, stream,
                     kp, vp, proj, ctxp, kexpp, vsump, gmaxb, nchunk);
  hipLaunchKernelGGL(perf_rescale, dim3(128 * 8), dim3(256), 0, stream,
                     ctxp, kexpp, vsump, kcw, ctxt, gmaxb, nchunk);
  hipLaunchKernelGGL(perf_qpass, dim3(128 * 16), dim3(256), 0, stream,
                     qp, proj, ctxt, kcw, outp);
}